// Round 1
// baseline (2292.256 us; speedup 1.0000x reference)
//
#include <hip/hip_runtime.h>
#include <cstdint>
#include <cstddef>

#define HD 128

__device__ __forceinline__ float wave_reduce_sum(float v) {
#pragma unroll
    for (int o = 1; o < 64; o <<= 1) v += __shfl_xor(v, o, 64);
    return v;
}

// ---------------- edge-index handling ----------------
// flag=1 -> data is int32, flag=0 -> int64 (hi words all zero since values < 2^31)
__global__ void detect_kernel(const unsigned* __restrict__ w, int* __restrict__ flag) {
    if (threadIdx.x == 0) *flag = 0;
    __syncthreads();
    unsigned v = w[2 * threadIdx.x + 1];
    if (v != 0u) atomicOr(flag, 1);
}

__global__ void convert_kernel(const void* __restrict__ raw, int E, const int* __restrict__ flag,
                               int* __restrict__ src, int* __restrict__ dst) {
    int i = blockIdx.x * 256 + threadIdx.x;
    if (i >= E) return;
    if (*flag) {
        const int* p = (const int*)raw;
        src[i] = p[i];
        dst[i] = p[E + i];
    } else {
        const long long* p = (const long long*)raw;
        src[i] = (int)p[i];
        dst[i] = (int)p[E + i];
    }
}

// ---------------- CSR build ----------------
__global__ void hist_kernel(const int* __restrict__ dst, int E, int* __restrict__ deg) {
    int i = blockIdx.x * 256 + threadIdx.x;
    if (i < E) atomicAdd(&deg[dst[i]], 1);
}

__global__ void scan_block_k(const int* __restrict__ deg, int* __restrict__ rowptr,
                             int* __restrict__ bsum, int n) {
    __shared__ int s[256];
    int tid = threadIdx.x;
    int i = blockIdx.x * 256 + tid;
    int v = (i < n) ? deg[i] : 0;
    s[tid] = v;
    __syncthreads();
#pragma unroll
    for (int o = 1; o < 256; o <<= 1) {
        int t = (tid >= o) ? s[tid - o] : 0;
        __syncthreads();
        s[tid] += t;
        __syncthreads();
    }
    if (i < n) rowptr[i] = s[tid] - v;  // exclusive within block
    if (tid == 255) bsum[blockIdx.x] = s[255];
}

__global__ void scan_bsums_k(const int* __restrict__ bsum, int nb, int* __restrict__ boff,
                             int* __restrict__ rowptr, int n, int E) {
    __shared__ int s[512];
    int tid = threadIdx.x;
    int v = (tid < nb) ? bsum[tid] : 0;
    s[tid] = v;
    __syncthreads();
#pragma unroll
    for (int o = 1; o < 512; o <<= 1) {
        int t = (tid >= o) ? s[tid - o] : 0;
        __syncthreads();
        s[tid] += t;
        __syncthreads();
    }
    if (tid < nb) boff[tid] = s[tid] - v;  // exclusive block offsets
    if (tid == 0) rowptr[n] = E;
}

__global__ void scan_add_k(int* __restrict__ rowptr, const int* __restrict__ boff,
                           int* __restrict__ cursor, int n) {
    int i = blockIdx.x * 256 + threadIdx.x;
    if (i < n) {
        int r = rowptr[i] + boff[blockIdx.x];
        rowptr[i] = r;
        cursor[i] = r;
    }
}

__global__ void scatter_k(const int* __restrict__ src, const int* __restrict__ dst, int E,
                          int* __restrict__ cursor, int* __restrict__ csr) {
    int i = blockIdx.x * 256 + threadIdx.x;
    if (i < E) {
        int j = atomicAdd(&cursor[dst[i]], 1);
        csr[j] = src[i];
    }
}

// ---------------- linear: Y = X@W + b (+ optional residual R) ----------------
// X [n,128], W [128,128] row-major (k, c), per-block tile 64 rows x 128 cols.
template <bool RESID>
__global__ __launch_bounds__(256) void linear_kernel(
    const float* __restrict__ X, const float* __restrict__ W,
    const float* __restrict__ bias, const float* __restrict__ Rres,
    float* __restrict__ Y, int n) {
    __shared__ __align__(16) float Xs[64][33];
    __shared__ __align__(16) float Ws[32][128];
    const int t = threadIdx.x;
    const int tx = t & 15;   // column group (8 cols)
    const int ty = t >> 4;   // row group (4 rows)
    const int rowBase = blockIdx.x * 64;

    float acc[4][8];
#pragma unroll
    for (int i = 0; i < 4; ++i)
#pragma unroll
        for (int j = 0; j < 8; ++j) acc[i][j] = 0.f;

    for (int k0 = 0; k0 < HD; k0 += 32) {
        // stage X tile: 64 rows x 32 k
#pragma unroll
        for (int i = 0; i < 2; ++i) {
            int f = t * 2 + i;         // 0..511 float4 slots
            int r = f >> 3;            // 0..63
            int k4 = (f & 7) * 4;      // 0..28
            int gr = rowBase + r;
            float4 xv = make_float4(0.f, 0.f, 0.f, 0.f);
            if (gr < n) xv = *(const float4*)&X[(size_t)gr * HD + k0 + k4];
            Xs[r][k4 + 0] = xv.x;
            Xs[r][k4 + 1] = xv.y;
            Xs[r][k4 + 2] = xv.z;
            Xs[r][k4 + 3] = xv.w;
        }
        // stage W chunk: 32 k x 128 c
#pragma unroll
        for (int i = 0; i < 4; ++i) {
            int f = i * 256 + t;       // 0..1023 float4 slots
            int kk = f >> 5;
            int c4 = (f & 31) * 4;
            *(float4*)&Ws[kk][c4] = *(const float4*)&W[(size_t)(k0 + kk) * HD + c4];
        }
        __syncthreads();
#pragma unroll 8
        for (int kk = 0; kk < 32; ++kk) {
            float xv[4];
#pragma unroll
            for (int i = 0; i < 4; ++i) xv[i] = Xs[ty * 4 + i][kk];
            float4 w0 = *(const float4*)&Ws[kk][tx * 8];
            float4 w1 = *(const float4*)&Ws[kk][tx * 8 + 4];
            float wv[8] = {w0.x, w0.y, w0.z, w0.w, w1.x, w1.y, w1.z, w1.w};
#pragma unroll
            for (int i = 0; i < 4; ++i)
#pragma unroll
                for (int j = 0; j < 8; ++j) acc[i][j] += xv[i] * wv[j];
        }
        __syncthreads();
    }
    const int c0 = tx * 8;
#pragma unroll
    for (int i = 0; i < 4; ++i) {
        int r = rowBase + ty * 4 + i;
        if (r < n) {
#pragma unroll
            for (int j = 0; j < 8; ++j) {
                float o = acc[i][j] + bias[c0 + j];
                if (RESID) o += Rres[(size_t)r * HD + c0 + j];
                Y[(size_t)r * HD + c0 + j] = o;
            }
        }
    }
}

// ---------------- fused edge attention + message aggregation ----------------
// one wave per dst node, online softmax (flash-style), CSR over incoming edges
__global__ __launch_bounds__(256) void attn_kernel(
    const float* __restrict__ Q, const float* __restrict__ K, const float* __restrict__ V,
    const int* __restrict__ rowptr, const int* __restrict__ csr_src,
    float* __restrict__ msg, int n) {
    int gt = blockIdx.x * 256 + threadIdx.x;
    int d = gt >> 6;
    int lane = threadIdx.x & 63;
    if (d >= n) return;
    int beg = rowptr[d], end = rowptr[d + 1];
    float2 q = *(const float2*)&Q[(size_t)d * HD + lane * 2];
    const float scale = 0.08838834764831845f;  // 1/sqrt(128)
    float m = -1e30f, ssum = 0.f;
    float2 acc = make_float2(0.f, 0.f);
    for (int j = beg; j < end; ++j) {
        int s = csr_src[j];
        float2 kv = *(const float2*)&K[(size_t)s * HD + lane * 2];
        float2 vv = *(const float2*)&V[(size_t)s * HD + lane * 2];
        float p = q.x * kv.x + q.y * kv.y;
        p = wave_reduce_sum(p) * scale;
        float mnew = fmaxf(m, p);
        float r = __expf(m - mnew);
        float e = __expf(p - mnew);
        ssum = ssum * r + e;
        acc.x = acc.x * r + e * vv.x;
        acc.y = acc.y * r + e * vv.y;
        m = mnew;
    }
    float inv = (end > beg) ? 1.f / ssum : 0.f;
    acc.x *= inv;
    acc.y *= inv;
    *(float2*)&msg[(size_t)d * HD + lane * 2] = acc;
}

// ---------------- layernorm over rows of 128 ----------------
__global__ __launch_bounds__(256) void ln_kernel(
    const float* __restrict__ X, const float* __restrict__ g, const float* __restrict__ b,
    float* __restrict__ Y, int n) {
    int gt = blockIdx.x * 256 + threadIdx.x;
    int row = gt >> 6;
    int lane = threadIdx.x & 63;
    if (row >= n) return;
    float2 x = *(const float2*)&X[(size_t)row * HD + lane * 2];
    float mu = wave_reduce_sum(x.x + x.y) * (1.f / 128.f);
    float dx = x.x - mu, dy = x.y - mu;
    float var = wave_reduce_sum(dx * dx + dy * dy) * (1.f / 128.f);
    float inv = rsqrtf(var + 1e-5f);
    int c = lane * 2;
    float2 gg = *(const float2*)&g[c];
    float2 bb = *(const float2*)&b[c];
    float2 y;
    y.x = dx * inv * gg.x + bb.x;
    y.y = dy * inv * gg.y + bb.y;
    *(float2*)&Y[(size_t)row * HD + c] = y;
}

// ---------------- launch ----------------
extern "C" void kernel_launch(void* const* d_in, const int* in_sizes, int n_in,
                              void* d_out, int out_size, void* d_ws, size_t ws_size,
                              hipStream_t stream) {
    const float* x    = (const float*)d_in[0];
    const void*  eix  = d_in[1];
    const float* Wn   = (const float*)d_in[2];
    const float* bn   = (const float*)d_in[3];
    const float* WQ   = (const float*)d_in[4];
    const float* bQ   = (const float*)d_in[5];
    const float* WK   = (const float*)d_in[6];
    const float* bK   = (const float*)d_in[7];
    const float* WV   = (const float*)d_in[8];
    const float* bV   = (const float*)d_in[9];
    const float* WO   = (const float*)d_in[10];
    const float* bO   = (const float*)d_in[11];
    const float* lng  = (const float*)d_in[12];
    const float* lnb  = (const float*)d_in[13];
    const float* Wout = (const float*)d_in[14];
    const float* bout = (const float*)d_in[15];

    const int n = in_sizes[0] / HD;
    const int E = in_sizes[1] / 2;
    const int L = 4;

    char* p = (char*)d_ws;
    auto alloc = [&](size_t bytes) -> void* {
        void* r = (void*)p;
        p += (bytes + 255) & ~(size_t)255;
        return r;
    };
    float* h    = (float*)alloc((size_t)n * HD * 4);
    float* q    = (float*)alloc((size_t)n * HD * 4);
    float* k    = (float*)alloc((size_t)n * HD * 4);
    float* v    = (float*)alloc((size_t)n * HD * 4);
    int* src32  = (int*)alloc((size_t)E * 4);
    int* dst32  = (int*)alloc((size_t)E * 4);
    int* csr    = (int*)alloc((size_t)E * 4);
    int* deg    = (int*)alloc((size_t)n * 4);
    int* rowptr = (int*)alloc((size_t)(n + 1) * 4);
    int* cursor = (int*)alloc((size_t)n * 4);
    int* bsum   = (int*)alloc(512 * 4);
    int* boff   = (int*)alloc(512 * 4);
    int* flag   = (int*)alloc(256);
    float* msg  = (float*)d_out;  // reused as scratch; overwritten by final linear

    const int nbE = (E + 255) / 256;
    const int NB  = (n + 255) / 256;
    const int nw  = (n + 3) / 4;    // wave-per-row kernels
    const int nl  = (n + 63) / 64;  // linear tiles

    detect_kernel<<<1, 256, 0, stream>>>((const unsigned*)eix, flag);
    convert_kernel<<<nbE, 256, 0, stream>>>(eix, E, flag, src32, dst32);
    hipMemsetAsync(deg, 0, (size_t)n * 4, stream);
    hist_kernel<<<nbE, 256, 0, stream>>>(dst32, E, deg);
    scan_block_k<<<NB, 256, 0, stream>>>(deg, rowptr, bsum, n);
    scan_bsums_k<<<1, 512, 0, stream>>>(bsum, NB, boff, rowptr, n, E);
    scan_add_k<<<NB, 256, 0, stream>>>(rowptr, boff, cursor, n);
    scatter_k<<<nbE, 256, 0, stream>>>(src32, dst32, E, cursor, csr);

    linear_kernel<false><<<nl, 256, 0, stream>>>(x, Wn, bn, nullptr, h, n);
    for (int l = 0; l < L; ++l) {
        const float* wq = WQ + (size_t)l * HD * HD;
        const float* wk = WK + (size_t)l * HD * HD;
        const float* wv = WV + (size_t)l * HD * HD;
        const float* wo = WO + (size_t)l * HD * HD;
        linear_kernel<false><<<nl, 256, 0, stream>>>(h, wq, bQ + l * HD, nullptr, q, n);
        linear_kernel<false><<<nl, 256, 0, stream>>>(h, wk, bK + l * HD, nullptr, k, n);
        linear_kernel<false><<<nl, 256, 0, stream>>>(h, wv, bV + l * HD, nullptr, v, n);
        attn_kernel<<<nw, 256, 0, stream>>>(q, k, v, rowptr, csr, msg, n);
        // tmp = h + msg@WO + bO  (stored in q, which is dead now)
        linear_kernel<true><<<nl, 256, 0, stream>>>(msg, wo, bO + l * HD, h, q, n);
        // h = LN(tmp)
        ln_kernel<<<nw, 256, 0, stream>>>(q, lng + l * HD, lnb + l * HD, h, n);
    }
    linear_kernel<false><<<nl, 256, 0, stream>>>(h, Wout, bout, nullptr, (float*)d_out, n);
}

// Round 2
// 1422.469 us; speedup vs baseline: 1.6115x; 1.6115x over previous
//
#include <hip/hip_runtime.h>
#include <cstdint>
#include <cstddef>

#define HD 128

typedef __attribute__((ext_vector_type(8))) short bf16x8;
typedef __attribute__((ext_vector_type(8))) unsigned short u16x8;
typedef __attribute__((ext_vector_type(4))) float f32x4;

__device__ __forceinline__ unsigned short f2bf(float x) {
    unsigned int b = __float_as_uint(x);
    b += 0x7FFFu + ((b >> 16) & 1u);
    return (unsigned short)(b >> 16);
}
__device__ __forceinline__ float bf2f(unsigned short u) {
    return __uint_as_float(((unsigned int)u) << 16);
}

// ---------------- edge-index handling ----------------
__global__ void detect_kernel(const unsigned* __restrict__ w, int* __restrict__ flag) {
    if (threadIdx.x == 0) *flag = 0;
    __syncthreads();
    unsigned v = w[2 * threadIdx.x + 1];
    if (v != 0u) atomicOr(flag, 1);
}

__global__ void convert_kernel(const void* __restrict__ raw, int E, const int* __restrict__ flag,
                               int* __restrict__ src, int* __restrict__ dst) {
    int i = blockIdx.x * 256 + threadIdx.x;
    if (i >= E) return;
    if (*flag) {
        const int* p = (const int*)raw;
        src[i] = p[i];
        dst[i] = p[E + i];
    } else {
        const long long* p = (const long long*)raw;
        src[i] = (int)p[i];
        dst[i] = (int)p[E + i];
    }
}

// ---------------- CSR build ----------------
__global__ void hist_kernel(const int* __restrict__ dst, int E, int* __restrict__ deg) {
    int i = blockIdx.x * 256 + threadIdx.x;
    if (i < E) atomicAdd(&deg[dst[i]], 1);
}

__global__ void scan_block_k(const int* __restrict__ deg, int* __restrict__ rowptr,
                             int* __restrict__ bsum, int n) {
    __shared__ int s[256];
    int tid = threadIdx.x;
    int i = blockIdx.x * 256 + tid;
    int v = (i < n) ? deg[i] : 0;
    s[tid] = v;
    __syncthreads();
#pragma unroll
    for (int o = 1; o < 256; o <<= 1) {
        int t = (tid >= o) ? s[tid - o] : 0;
        __syncthreads();
        s[tid] += t;
        __syncthreads();
    }
    if (i < n) rowptr[i] = s[tid] - v;
    if (tid == 255) bsum[blockIdx.x] = s[255];
}

__global__ void scan_bsums_k(const int* __restrict__ bsum, int nb, int* __restrict__ boff,
                             int* __restrict__ rowptr, int n, int E) {
    __shared__ int s[512];
    int tid = threadIdx.x;
    int v = (tid < nb) ? bsum[tid] : 0;
    s[tid] = v;
    __syncthreads();
#pragma unroll
    for (int o = 1; o < 512; o <<= 1) {
        int t = (tid >= o) ? s[tid - o] : 0;
        __syncthreads();
        s[tid] += t;
        __syncthreads();
    }
    if (tid < nb) boff[tid] = s[tid] - v;
    if (tid == 0) rowptr[n] = E;
}

__global__ void scan_add_k(int* __restrict__ rowptr, const int* __restrict__ boff,
                           int* __restrict__ cursor, int n) {
    int i = blockIdx.x * 256 + threadIdx.x;
    if (i < n) {
        int r = rowptr[i] + boff[blockIdx.x];
        rowptr[i] = r;
        cursor[i] = r;
    }
}

__global__ void scatter_k(const int* __restrict__ src, const int* __restrict__ dst, int E,
                          int* __restrict__ cursor, int* __restrict__ csr) {
    int i = blockIdx.x * 256 + threadIdx.x;
    if (i < E) {
        int j = atomicAdd(&cursor[dst[i]], 1);
        csr[j] = src[i];
    }
}

// ---------------- weight transpose+convert: Wt[c][k] = W[k][c] (bf16) ----------------
__global__ void wtrans_kernel(const float* __restrict__ src, unsigned short* __restrict__ dst,
                              int nmat) {
    int i = blockIdx.x * 256 + threadIdx.x;
    int m = i >> 14;
    if (m >= nmat) return;
    int r = i & 16383;
    int k = r >> 7, c = r & 127;
    dst[(size_t)m * 16384 + (size_t)c * HD + k] = f2bf(src[(size_t)m * 16384 + r]);
}

// ---------------- MFMA linear, one wave = 16 rows x 128 cols, K=128 ----------------
// A: lane holds X[waveBase + (l&15)][ks*32 + (l>>4)*8 + j]   (contiguous-K bf16x8)
// B: lane holds Wt[nf*16 + (l&15)][ks*32 + (l>>4)*8 + j]     (W^T rows = contiguous-K)
// D: lane l, reg r -> row = waveBase + (l>>4)*4 + r, col = nf*16 + (l&15)
template <bool AIN_F32, bool RESID_LN, bool OUT_F32, bool OUT_BF>
__global__ __launch_bounds__(256) void lin_kernel(
    const void* __restrict__ Xin, const unsigned short* __restrict__ Wt,
    const float* __restrict__ bias,
    const float* __restrict__ lng, const float* __restrict__ lnb,
    float* __restrict__ Rf, float* __restrict__ Yf, unsigned short* __restrict__ Yb, int n) {
    const int tid = threadIdx.x;
    const int w = tid >> 6;
    const int lane = tid & 63;
    const int t = lane & 15, g = lane >> 4;
    const int waveBase = blockIdx.x * 64 + w * 16;
    const int arow = waveBase + t;
    const bool rowOK = arow < n;

    f32x4 acc[8];
#pragma unroll
    for (int nf = 0; nf < 8; ++nf) acc[nf] = (f32x4){0.f, 0.f, 0.f, 0.f};

#pragma unroll
    for (int ks = 0; ks < 4; ++ks) {
        const int k = ks * 32 + g * 8;
        bf16x8 a = (bf16x8){0, 0, 0, 0, 0, 0, 0, 0};
        if (rowOK) {
            if (AIN_F32) {
                const float* Xf = (const float*)Xin;
                float4 x0 = *(const float4*)&Xf[(size_t)arow * HD + k];
                float4 x1 = *(const float4*)&Xf[(size_t)arow * HD + k + 4];
                a[0] = (short)f2bf(x0.x); a[1] = (short)f2bf(x0.y);
                a[2] = (short)f2bf(x0.z); a[3] = (short)f2bf(x0.w);
                a[4] = (short)f2bf(x1.x); a[5] = (short)f2bf(x1.y);
                a[6] = (short)f2bf(x1.z); a[7] = (short)f2bf(x1.w);
            } else {
                const unsigned short* Xb = (const unsigned short*)Xin;
                a = *(const bf16x8*)&Xb[(size_t)arow * HD + k];
            }
        }
#pragma unroll
        for (int nf = 0; nf < 8; ++nf) {
            bf16x8 b = *(const bf16x8*)&Wt[(size_t)(nf * 16 + t) * HD + k];
            acc[nf] = __builtin_amdgcn_mfma_f32_16x16x32_bf16(a, b, acc[nf], 0, 0, 0);
        }
    }

    // epilogue
    float v[8][4];
#pragma unroll
    for (int nf = 0; nf < 8; ++nf) {
        const int col = nf * 16 + t;
        const float bv = bias[col];
#pragma unroll
        for (int r = 0; r < 4; ++r) {
            float x = acc[nf][r] + bv;
            if (RESID_LN) {
                const int row = waveBase + g * 4 + r;
                if (row < n) x += Rf[(size_t)row * HD + col];
            }
            v[nf][r] = x;
        }
    }

    if (RESID_LN) {
#pragma unroll
        for (int r = 0; r < 4; ++r) {
            float s = 0.f, sq = 0.f;
#pragma unroll
            for (int nf = 0; nf < 8; ++nf) { s += v[nf][r]; sq += v[nf][r] * v[nf][r]; }
#pragma unroll
            for (int mask = 1; mask < 16; mask <<= 1) {
                s += __shfl_xor(s, mask, 64);
                sq += __shfl_xor(sq, mask, 64);
            }
            const float mu = s * (1.f / 128.f);
            const float var = sq * (1.f / 128.f) - mu * mu;
            const float inv = rsqrtf(var + 1e-5f);
#pragma unroll
            for (int nf = 0; nf < 8; ++nf) {
                const int col = nf * 16 + t;
                v[nf][r] = (v[nf][r] - mu) * inv * lng[col] + lnb[col];
            }
        }
    }

#pragma unroll
    for (int r = 0; r < 4; ++r) {
        const int row = waveBase + g * 4 + r;
        if (row < n) {
#pragma unroll
            for (int nf = 0; nf < 8; ++nf) {
                const int col = nf * 16 + t;
                if (OUT_F32) Yf[(size_t)row * HD + col] = v[nf][r];
                if (OUT_BF) Yb[(size_t)row * HD + col] = f2bf(v[nf][r]);
            }
        }
    }
}

// ---------------- fused edge attention, bf16, 4 edges in flight per wave ----------------
__global__ __launch_bounds__(256) void attn_kernel(
    const unsigned short* __restrict__ Qb, const unsigned short* __restrict__ Kb,
    const unsigned short* __restrict__ Vb,
    const int* __restrict__ rowptr, const int* __restrict__ csr,
    unsigned short* __restrict__ Mb, int n) {
    const int d = (blockIdx.x * 256 + threadIdx.x) >> 6;
    if (d >= n) return;
    const int lane = threadIdx.x & 63;
    const int t = lane & 15, g = lane >> 4;
    const int beg = rowptr[d], end = rowptr[d + 1];

    float qv[8];
    {
        u16x8 qu = *(const u16x8*)&Qb[(size_t)d * HD + t * 8];
#pragma unroll
        for (int j = 0; j < 8; ++j) qv[j] = bf2f(qu[j]);
    }
    const float scale = 0.08838834764831845f;  // 1/sqrt(128)
    float m = -1e30f, ss = 0.f;
    float acc[8];
#pragma unroll
    for (int j = 0; j < 8; ++j) acc[j] = 0.f;

    const int nit = (end - beg + 3) >> 2;
    for (int it = 0; it < nit; ++it) {
        const int idx = beg + it * 4 + g;
        const bool act = idx < end;
        const int s = act ? csr[idx] : 0;
        u16x8 ku = *(const u16x8*)&Kb[(size_t)s * HD + t * 8];
        u16x8 vu = *(const u16x8*)&Vb[(size_t)s * HD + t * 8];
        float p = 0.f;
#pragma unroll
        for (int j = 0; j < 8; ++j) p += bf2f(ku[j]) * qv[j];
#pragma unroll
        for (int mask = 1; mask < 16; mask <<= 1) p += __shfl_xor(p, mask, 64);
        p *= scale;
        const float mnew = act ? fmaxf(m, p) : m;
        const float r = __expf(m - mnew);
        const float e = act ? __expf(p - mnew) : 0.f;
        ss = ss * r + e;
#pragma unroll
        for (int j = 0; j < 8; ++j) acc[j] = acc[j] * r + e * bf2f(vu[j]);
        m = mnew;
    }

    // merge the 4 groups (masks 16, 32)
#pragma unroll
    for (int mask = 16; mask <= 32; mask <<= 1) {
        const float mo = __shfl_xor(m, mask, 64);
        const float sso = __shfl_xor(ss, mask, 64);
        const float M = fmaxf(m, mo);
        const float r1 = __expf(m - M), r2 = __expf(mo - M);
        ss = ss * r1 + sso * r2;
#pragma unroll
        for (int j = 0; j < 8; ++j) {
            const float ao = __shfl_xor(acc[j], mask, 64);
            acc[j] = acc[j] * r1 + ao * r2;
        }
        m = M;
    }

    const float inv = (end > beg) ? 1.f / ss : 0.f;
    if (g == 0) {
        u16x8 o;
#pragma unroll
        for (int j = 0; j < 8; ++j) o[j] = f2bf(acc[j] * inv);
        *(u16x8*)&Mb[(size_t)d * HD + t * 8] = o;
    }
}

// ---------------- launch ----------------
extern "C" void kernel_launch(void* const* d_in, const int* in_sizes, int n_in,
                              void* d_out, int out_size, void* d_ws, size_t ws_size,
                              hipStream_t stream) {
    const float* x    = (const float*)d_in[0];
    const void*  eix  = d_in[1];
    const float* Wn   = (const float*)d_in[2];
    const float* bn   = (const float*)d_in[3];
    const float* WQ   = (const float*)d_in[4];
    const float* bQ   = (const float*)d_in[5];
    const float* WK   = (const float*)d_in[6];
    const float* bK   = (const float*)d_in[7];
    const float* WV   = (const float*)d_in[8];
    const float* bV   = (const float*)d_in[9];
    const float* WO   = (const float*)d_in[10];
    const float* bO   = (const float*)d_in[11];
    const float* lng  = (const float*)d_in[12];
    const float* lnb  = (const float*)d_in[13];
    const float* Wout = (const float*)d_in[14];
    const float* bout = (const float*)d_in[15];

    const int n = in_sizes[0] / HD;
    const int E = in_sizes[1] / 2;
    const int L = 4;

    char* p = (char*)d_ws;
    auto alloc = [&](size_t bytes) -> void* {
        void* r = (void*)p;
        p += (bytes + 255) & ~(size_t)255;
        return r;
    };
    float* h             = (float*)alloc((size_t)n * HD * 4);
    unsigned short* hb   = (unsigned short*)alloc((size_t)n * HD * 2);
    unsigned short* qb   = (unsigned short*)alloc((size_t)n * HD * 2);
    unsigned short* kb   = (unsigned short*)alloc((size_t)n * HD * 2);
    unsigned short* vb   = (unsigned short*)alloc((size_t)n * HD * 2);
    unsigned short* mb   = (unsigned short*)alloc((size_t)n * HD * 2);
    int* src32  = (int*)alloc((size_t)E * 4);
    int* dst32  = (int*)alloc((size_t)E * 4);
    int* csr    = (int*)alloc((size_t)E * 4);
    int* deg    = (int*)alloc((size_t)n * 4);
    int* rowptr = (int*)alloc((size_t)(n + 1) * 4);
    int* cursor = (int*)alloc((size_t)n * 4);
    int* bsum   = (int*)alloc(512 * 4);
    int* boff   = (int*)alloc(512 * 4);
    int* flag   = (int*)alloc(256);
    unsigned short* wn_t = (unsigned short*)alloc(16384 * 2);
    unsigned short* wq_t = (unsigned short*)alloc(4 * 16384 * 2);
    unsigned short* wk_t = (unsigned short*)alloc(4 * 16384 * 2);
    unsigned short* wv_t = (unsigned short*)alloc(4 * 16384 * 2);
    unsigned short* wo_t = (unsigned short*)alloc(4 * 16384 * 2);
    unsigned short* wout_t = (unsigned short*)alloc(16384 * 2);

    const int nbE = (E + 255) / 256;
    const int NB  = (n + 255) / 256;
    const int nw  = (n + 3) / 4;    // wave-per-node kernels
    const int nl  = (n + 63) / 64;  // MFMA linear tiles
    const int w1  = (16384 + 255) / 256;
    const int w4  = (4 * 16384 + 255) / 256;

    detect_kernel<<<1, 256, 0, stream>>>((const unsigned*)eix, flag);
    convert_kernel<<<nbE, 256, 0, stream>>>(eix, E, flag, src32, dst32);
    hipMemsetAsync(deg, 0, (size_t)n * 4, stream);
    hist_kernel<<<nbE, 256, 0, stream>>>(dst32, E, deg);
    scan_block_k<<<NB, 256, 0, stream>>>(deg, rowptr, bsum, n);
    scan_bsums_k<<<1, 512, 0, stream>>>(bsum, NB, boff, rowptr, n, E);
    scan_add_k<<<NB, 256, 0, stream>>>(rowptr, boff, cursor, n);
    scatter_k<<<nbE, 256, 0, stream>>>(src32, dst32, E, cursor, csr);

    wtrans_kernel<<<w1, 256, 0, stream>>>(Wn, wn_t, 1);
    wtrans_kernel<<<w4, 256, 0, stream>>>(WQ, wq_t, 4);
    wtrans_kernel<<<w4, 256, 0, stream>>>(WK, wk_t, 4);
    wtrans_kernel<<<w4, 256, 0, stream>>>(WV, wv_t, 4);
    wtrans_kernel<<<w4, 256, 0, stream>>>(WO, wo_t, 4);
    wtrans_kernel<<<w1, 256, 0, stream>>>(Wout, wout_t, 1);

    // h = x @ Wn + bn  (fp32 + bf16 outputs)
    lin_kernel<true, false, true, true><<<nl, 256, 0, stream>>>(
        x, wn_t, bn, nullptr, nullptr, nullptr, h, hb, n);

    for (int l = 0; l < L; ++l) {
        lin_kernel<false, false, false, true><<<nl, 256, 0, stream>>>(
            hb, wq_t + (size_t)l * 16384, bQ + l * HD, nullptr, nullptr, nullptr, nullptr, qb, n);
        lin_kernel<false, false, false, true><<<nl, 256, 0, stream>>>(
            hb, wk_t + (size_t)l * 16384, bK + l * HD, nullptr, nullptr, nullptr, nullptr, kb, n);
        lin_kernel<false, false, false, true><<<nl, 256, 0, stream>>>(
            hb, wv_t + (size_t)l * 16384, bV + l * HD, nullptr, nullptr, nullptr, nullptr, vb, n);
        attn_kernel<<<nw, 256, 0, stream>>>(qb, kb, vb, rowptr, csr, mb, n);
        // h = LN(h + mb@WO + bO), also write hb
        lin_kernel<false, true, true, true><<<nl, 256, 0, stream>>>(
            mb, wo_t + (size_t)l * 16384, bO + l * HD, lng + l * HD, lnb + l * HD, h, h, hb, n);
    }
    lin_kernel<false, false, true, false><<<nl, 256, 0, stream>>>(
        hb, wout_t, bout, nullptr, nullptr, nullptr, (float*)d_out, nullptr, n);
}

// Round 3
// 1217.870 us; speedup vs baseline: 1.8822x; 1.1680x over previous
//
#include <hip/hip_runtime.h>
#include <cstdint>
#include <cstddef>

#define HD 128

typedef __attribute__((ext_vector_type(8))) short bf16x8;
typedef __attribute__((ext_vector_type(8))) unsigned short u16x8;
typedef __attribute__((ext_vector_type(4))) float f32x4;

__device__ __forceinline__ unsigned short f2bf(float x) {
    unsigned int b = __float_as_uint(x);
    b += 0x7FFFu + ((b >> 16) & 1u);
    return (unsigned short)(b >> 16);
}
__device__ __forceinline__ float bf2f(unsigned short u) {
    return __uint_as_float(((unsigned int)u) << 16);
}

// ---------------- edge-index handling ----------------
__global__ void detect_kernel(const unsigned* __restrict__ w, int* __restrict__ flag) {
    if (threadIdx.x == 0) *flag = 0;
    __syncthreads();
    unsigned v = w[2 * threadIdx.x + 1];
    if (v != 0u) atomicOr(flag, 1);
}

__global__ void convert_kernel(const void* __restrict__ raw, int E, const int* __restrict__ flag,
                               int* __restrict__ src, int* __restrict__ dst) {
    int i = blockIdx.x * 256 + threadIdx.x;
    if (i >= E) return;
    if (*flag) {
        const int* p = (const int*)raw;
        src[i] = p[i];
        dst[i] = p[E + i];
    } else {
        const long long* p = (const long long*)raw;
        src[i] = (int)p[i];
        dst[i] = (int)p[E + i];
    }
}

// ---------------- CSR build: two-level bucket sort (bin = dst>>9) ----------------
#define EPB 4096  // edges per block in pass 1

__global__ __launch_bounds__(256) void p1_count(const int* __restrict__ dst, int E,
                                                int* __restrict__ tot, int nbins) {
    __shared__ int h[256];
    const int tid = threadIdx.x;
    h[tid] = 0;
    __syncthreads();
    const int base = blockIdx.x * EPB;
    const int lim = min(E, base + EPB);
    for (int i = base + tid; i < lim; i += 256) atomicAdd(&h[dst[i] >> 9], 1);
    __syncthreads();
    if (tid < nbins && h[tid]) atomicAdd(&tot[tid], h[tid]);
}

__global__ __launch_bounds__(256) void p1_scan(const int* __restrict__ tot,
                                               int* __restrict__ base, int* __restrict__ cursor,
                                               int* __restrict__ rowptr, int nbins, int n, int E) {
    __shared__ int s[256];
    const int tid = threadIdx.x;
    const int v = (tid < nbins) ? tot[tid] : 0;
    s[tid] = v;
    __syncthreads();
#pragma unroll
    for (int o = 1; o < 256; o <<= 1) {
        int t = (tid >= o) ? s[tid - o] : 0;
        __syncthreads();
        s[tid] += t;
        __syncthreads();
    }
    if (tid < nbins) {
        base[tid] = s[tid] - v;
        cursor[tid] = s[tid] - v;
    }
    if (tid == 0) {
        base[nbins] = E;
        rowptr[n] = E;
    }
}

__global__ __launch_bounds__(256) void p1_scatter(const int* __restrict__ src,
                                                  const int* __restrict__ dst, int E,
                                                  int* __restrict__ cursor,
                                                  int* __restrict__ ssrc, int* __restrict__ sdst) {
    __shared__ int h[256];
    __shared__ int cur[256];
    const int tid = threadIdx.x;
    h[tid] = 0;
    __syncthreads();
    const int base = blockIdx.x * EPB;
    const int lim = min(E, base + EPB);
    for (int i = base + tid; i < lim; i += 256) atomicAdd(&h[dst[i] >> 9], 1);
    __syncthreads();
    if (h[tid]) cur[tid] = atomicAdd(&cursor[tid], h[tid]);
    __syncthreads();
    for (int i = base + tid; i < lim; i += 256) {
        const int d = dst[i];
        const int pos = atomicAdd(&cur[d >> 9], 1);
        sdst[pos] = d;
        ssrc[pos] = src[i];
    }
}

// one block per coarse bucket: exact-dst grouping + rowptr, all in LDS
__global__ __launch_bounds__(256) void p2_build(const int* __restrict__ sdst,
                                                const int* __restrict__ ssrc,
                                                const int* __restrict__ bucket_base,
                                                int* __restrict__ rowptr, int* __restrict__ csr,
                                                int n) {
    const int bin = blockIdx.x;
    const int b0 = bucket_base[bin], b1 = bucket_base[bin + 1];
    __shared__ int cnt[512];
    __shared__ int ps[256];
    __shared__ int cur[512];
    const int tid = threadIdx.x;
    cnt[tid] = 0;
    cnt[tid + 256] = 0;
    __syncthreads();
    for (int e = b0 + tid; e < b1; e += 256) atomicAdd(&cnt[sdst[e] & 511], 1);
    __syncthreads();
    const int a = cnt[2 * tid], b = cnt[2 * tid + 1];
    ps[tid] = a + b;
    __syncthreads();
#pragma unroll
    for (int o = 1; o < 256; o <<= 1) {
        int t = (tid >= o) ? ps[tid - o] : 0;
        __syncthreads();
        ps[tid] += t;
        __syncthreads();
    }
    const int e0 = ps[tid] - (a + b);  // exclusive
    const int e1 = e0 + a;
    const int v0 = bin * 512 + 2 * tid;
    if (v0 < n) rowptr[v0] = b0 + e0;
    if (v0 + 1 < n) rowptr[v0 + 1] = b0 + e1;
    cur[2 * tid] = b0 + e0;
    cur[2 * tid + 1] = b0 + e1;
    __syncthreads();
    for (int e = b0 + tid; e < b1; e += 256) {
        const int pos = atomicAdd(&cur[sdst[e] & 511], 1);
        csr[pos] = ssrc[e];
    }
}

// ---------------- weight transpose+convert: Wt[c][k] = W[k][c] (bf16) ----------------
__global__ void wtrans_kernel(const float* __restrict__ src, unsigned short* __restrict__ dst,
                              int nmat) {
    int i = blockIdx.x * 256 + threadIdx.x;
    int m = i >> 14;
    if (m >= nmat) return;
    int r = i & 16383;
    int k = r >> 7, c = r & 127;
    dst[(size_t)m * 16384 + (size_t)c * HD + k] = f2bf(src[(size_t)m * 16384 + r]);
}

// ---------------- MFMA linear, one wave = 16 rows x 128 cols, K=128 ----------------
// A: lane holds X[waveBase + (l&15)][ks*32 + (l>>4)*8 + j]   (contiguous-K bf16x8)
// B: lane holds Wt[nf*16 + (l&15)][ks*32 + (l>>4)*8 + j]     (W^T rows = contiguous-K)
// D: lane l, reg r -> row = waveBase + (l>>4)*4 + r, col = nf*16 + (l&15)
template <bool AIN_F32, bool RESID_LN, bool OUT_F32, bool OUT_BF>
__global__ __launch_bounds__(256) void lin_kernel(
    const void* __restrict__ Xin, const unsigned short* __restrict__ Wt,
    const float* __restrict__ bias,
    const float* __restrict__ lng, const float* __restrict__ lnb,
    const unsigned short* __restrict__ Rb, float* __restrict__ Yf,
    unsigned short* __restrict__ Yb, int n) {
    const int tid = threadIdx.x;
    const int w = tid >> 6;
    const int lane = tid & 63;
    const int t = lane & 15, g = lane >> 4;
    const int waveBase = blockIdx.x * 64 + w * 16;
    const int arow = waveBase + t;
    const bool rowOK = arow < n;

    bf16x8 af[4];
#pragma unroll
    for (int ks = 0; ks < 4; ++ks) {
        const int k = ks * 32 + g * 8;
        bf16x8 a = (bf16x8){0, 0, 0, 0, 0, 0, 0, 0};
        if (rowOK) {
            if (AIN_F32) {
                const float* Xf = (const float*)Xin;
                float4 x0 = *(const float4*)&Xf[(size_t)arow * HD + k];
                float4 x1 = *(const float4*)&Xf[(size_t)arow * HD + k + 4];
                a[0] = (short)f2bf(x0.x); a[1] = (short)f2bf(x0.y);
                a[2] = (short)f2bf(x0.z); a[3] = (short)f2bf(x0.w);
                a[4] = (short)f2bf(x1.x); a[5] = (short)f2bf(x1.y);
                a[6] = (short)f2bf(x1.z); a[7] = (short)f2bf(x1.w);
            } else {
                const unsigned short* Xb = (const unsigned short*)Xin;
                a = *(const bf16x8*)&Xb[(size_t)arow * HD + k];
            }
        }
        af[ks] = a;
    }

    f32x4 acc[8];
#pragma unroll
    for (int nf = 0; nf < 8; ++nf) acc[nf] = (f32x4){0.f, 0.f, 0.f, 0.f};
#pragma unroll
    for (int ks = 0; ks < 4; ++ks) {
        const int k = ks * 32 + g * 8;
#pragma unroll
        for (int nf = 0; nf < 8; ++nf) {
            bf16x8 b = *(const bf16x8*)&Wt[(size_t)(nf * 16 + t) * HD + k];
            acc[nf] = __builtin_amdgcn_mfma_f32_16x16x32_bf16(af[ks], b, acc[nf], 0, 0, 0);
        }
    }

    float v[8][4];
#pragma unroll
    for (int nf = 0; nf < 8; ++nf) {
        const int col = nf * 16 + t;
        const float bv = bias[col];
#pragma unroll
        for (int r = 0; r < 4; ++r) {
            float x = acc[nf][r] + bv;
            if (RESID_LN) {
                const int row = waveBase + g * 4 + r;
                if (row < n) x += bf2f(Rb[(size_t)row * HD + col]);
            }
            v[nf][r] = x;
        }
    }

    if (RESID_LN) {
#pragma unroll
        for (int r = 0; r < 4; ++r) {
            float s = 0.f, sq = 0.f;
#pragma unroll
            for (int nf = 0; nf < 8; ++nf) { s += v[nf][r]; sq += v[nf][r] * v[nf][r]; }
#pragma unroll
            for (int mask = 1; mask < 16; mask <<= 1) {
                s += __shfl_xor(s, mask, 64);
                sq += __shfl_xor(sq, mask, 64);
            }
            const float mu = s * (1.f / 128.f);
            const float var = sq * (1.f / 128.f) - mu * mu;
            const float inv = rsqrtf(var + 1e-5f);
#pragma unroll
            for (int nf = 0; nf < 8; ++nf) {
                const int col = nf * 16 + t;
                v[nf][r] = (v[nf][r] - mu) * inv * lng[col] + lnb[col];
            }
        }
    }

#pragma unroll
    for (int r = 0; r < 4; ++r) {
        const int row = waveBase + g * 4 + r;
        if (row < n) {
#pragma unroll
            for (int nf = 0; nf < 8; ++nf) {
                const int col = nf * 16 + t;
                if (OUT_F32) Yf[(size_t)row * HD + col] = v[nf][r];
                if (OUT_BF) Yb[(size_t)row * HD + col] = f2bf(v[nf][r]);
            }
        }
    }
}

// ---------------- fused QKV: 3 GEMMs sharing the A fragments ----------------
__global__ __launch_bounds__(256) void lin3_kernel(
    const unsigned short* __restrict__ Xb,
    const unsigned short* __restrict__ W0, const unsigned short* __restrict__ W1,
    const unsigned short* __restrict__ W2,
    const float* __restrict__ b0, const float* __restrict__ b1, const float* __restrict__ b2,
    unsigned short* __restrict__ Y0, unsigned short* __restrict__ Y1,
    unsigned short* __restrict__ Y2, int n) {
    const int tid = threadIdx.x;
    const int w = tid >> 6;
    const int lane = tid & 63;
    const int t = lane & 15, g = lane >> 4;
    const int waveBase = blockIdx.x * 64 + w * 16;
    const int arow = waveBase + t;
    const bool rowOK = arow < n;

    bf16x8 af[4];
#pragma unroll
    for (int ks = 0; ks < 4; ++ks) {
        bf16x8 a = (bf16x8){0, 0, 0, 0, 0, 0, 0, 0};
        if (rowOK) a = *(const bf16x8*)&Xb[(size_t)arow * HD + ks * 32 + g * 8];
        af[ks] = a;
    }

    const unsigned short* Ws[3] = {W0, W1, W2};
    const float* bs[3] = {b0, b1, b2};
    unsigned short* Ys[3] = {Y0, Y1, Y2};

#pragma unroll
    for (int mat = 0; mat < 3; ++mat) {
        f32x4 acc[8];
#pragma unroll
        for (int nf = 0; nf < 8; ++nf) acc[nf] = (f32x4){0.f, 0.f, 0.f, 0.f};
#pragma unroll
        for (int ks = 0; ks < 4; ++ks) {
            const int k = ks * 32 + g * 8;
#pragma unroll
            for (int nf = 0; nf < 8; ++nf) {
                bf16x8 b = *(const bf16x8*)&Ws[mat][(size_t)(nf * 16 + t) * HD + k];
                acc[nf] = __builtin_amdgcn_mfma_f32_16x16x32_bf16(af[ks], b, acc[nf], 0, 0, 0);
            }
        }
#pragma unroll
        for (int r = 0; r < 4; ++r) {
            const int row = waveBase + g * 4 + r;
            if (row < n) {
                u16x8 o;
#pragma unroll
                for (int nf = 0; nf < 8; ++nf) o[nf] = 0;  // placate compiler
#pragma unroll
                for (int nf = 0; nf < 8; ++nf) {
                    const int col = nf * 16 + t;
                    Ys[mat][(size_t)row * HD + col] = f2bf(acc[nf][r] + bs[mat][col]);
                }
                (void)o;
            }
        }
    }
}

// ---------------- fused edge attention, bf16, 4 edges in flight per wave ----------------
__global__ __launch_bounds__(256) void attn_kernel(
    const unsigned short* __restrict__ Qb, const unsigned short* __restrict__ Kb,
    const unsigned short* __restrict__ Vb,
    const int* __restrict__ rowptr, const int* __restrict__ csr,
    unsigned short* __restrict__ Mb, int n) {
    const int d = (blockIdx.x * 256 + threadIdx.x) >> 6;
    if (d >= n) return;
    const int lane = threadIdx.x & 63;
    const int t = lane & 15, g = lane >> 4;
    const int beg = rowptr[d], end = rowptr[d + 1];

    float qv[8];
    {
        u16x8 qu = *(const u16x8*)&Qb[(size_t)d * HD + t * 8];
#pragma unroll
        for (int j = 0; j < 8; ++j) qv[j] = bf2f(qu[j]);
    }
    const float scale = 0.08838834764831845f;  // 1/sqrt(128)
    float m = -1e30f, ss = 0.f;
    float acc[8];
#pragma unroll
    for (int j = 0; j < 8; ++j) acc[j] = 0.f;

    const int nit = (end - beg + 3) >> 2;
    for (int it = 0; it < nit; ++it) {
        const int idx = beg + it * 4 + g;
        const bool act = idx < end;
        const int s = act ? csr[idx] : 0;
        u16x8 ku = *(const u16x8*)&Kb[(size_t)s * HD + t * 8];
        u16x8 vu = *(const u16x8*)&Vb[(size_t)s * HD + t * 8];
        float p = 0.f;
#pragma unroll
        for (int j = 0; j < 8; ++j) p += bf2f(ku[j]) * qv[j];
#pragma unroll
        for (int mask = 1; mask < 16; mask <<= 1) p += __shfl_xor(p, mask, 64);
        p *= scale;
        const float mnew = act ? fmaxf(m, p) : m;
        const float r = __expf(m - mnew);
        const float e = act ? __expf(p - mnew) : 0.f;
        ss = ss * r + e;
#pragma unroll
        for (int j = 0; j < 8; ++j) acc[j] = acc[j] * r + e * bf2f(vu[j]);
        m = mnew;
    }

#pragma unroll
    for (int mask = 16; mask <= 32; mask <<= 1) {
        const float mo = __shfl_xor(m, mask, 64);
        const float sso = __shfl_xor(ss, mask, 64);
        const float M = fmaxf(m, mo);
        const float r1 = __expf(m - M), r2 = __expf(mo - M);
        ss = ss * r1 + sso * r2;
#pragma unroll
        for (int j = 0; j < 8; ++j) {
            const float ao = __shfl_xor(acc[j], mask, 64);
            acc[j] = acc[j] * r1 + ao * r2;
        }
        m = M;
    }

    const float inv = (end > beg) ? 1.f / ss : 0.f;
    if (g == 0) {
        u16x8 o;
#pragma unroll
        for (int j = 0; j < 8; ++j) o[j] = f2bf(acc[j] * inv);
        *(u16x8*)&Mb[(size_t)d * HD + t * 8] = o;
    }
}

// ---------------- launch ----------------
extern "C" void kernel_launch(void* const* d_in, const int* in_sizes, int n_in,
                              void* d_out, int out_size, void* d_ws, size_t ws_size,
                              hipStream_t stream) {
    const float* x    = (const float*)d_in[0];
    const void*  eix  = d_in[1];
    const float* Wn   = (const float*)d_in[2];
    const float* bn   = (const float*)d_in[3];
    const float* WQ   = (const float*)d_in[4];
    const float* bQ   = (const float*)d_in[5];
    const float* WK   = (const float*)d_in[6];
    const float* bK   = (const float*)d_in[7];
    const float* WV   = (const float*)d_in[8];
    const float* bV   = (const float*)d_in[9];
    const float* WO   = (const float*)d_in[10];
    const float* bO   = (const float*)d_in[11];
    const float* lng  = (const float*)d_in[12];
    const float* lnb  = (const float*)d_in[13];
    const float* Wout = (const float*)d_in[14];
    const float* bout = (const float*)d_in[15];

    const int n = in_sizes[0] / HD;
    const int E = in_sizes[1] / 2;
    const int L = 4;
    const int NBINS = (n + 511) >> 9;  // 196 for n=100k (fits 256-wide LDS hist while n<=131072)

    char* p = (char*)d_ws;
    auto alloc = [&](size_t bytes) -> void* {
        void* r = (void*)p;
        p += (bytes + 255) & ~(size_t)255;
        return r;
    };
    unsigned short* hb = (unsigned short*)alloc((size_t)n * HD * 2);
    unsigned short* qb = (unsigned short*)alloc((size_t)n * HD * 2);
    unsigned short* kb = (unsigned short*)alloc((size_t)n * HD * 2);
    unsigned short* vb = (unsigned short*)alloc((size_t)n * HD * 2);
    unsigned short* mb = (unsigned short*)alloc((size_t)n * HD * 2);
    int* src32  = (int*)alloc((size_t)E * 4);
    int* dst32  = (int*)alloc((size_t)E * 4);
    int* ssrc   = (int*)alloc((size_t)E * 4);
    int* sdst   = (int*)alloc((size_t)E * 4);
    int* csr    = (int*)alloc((size_t)E * 4);
    int* rowptr = (int*)alloc((size_t)(n + 1) * 4);
    int* btot   = (int*)alloc(256 * 4);
    int* bbase  = (int*)alloc(257 * 4);
    int* bcur   = (int*)alloc(256 * 4);
    int* flag   = (int*)alloc(256);
    unsigned short* wn_t   = (unsigned short*)alloc(16384 * 2);
    unsigned short* wq_t   = (unsigned short*)alloc(4 * 16384 * 2);
    unsigned short* wk_t   = (unsigned short*)alloc(4 * 16384 * 2);
    unsigned short* wv_t   = (unsigned short*)alloc(4 * 16384 * 2);
    unsigned short* wo_t   = (unsigned short*)alloc(4 * 16384 * 2);
    unsigned short* wout_t = (unsigned short*)alloc(16384 * 2);

    const int nbE = (E + 255) / 256;
    const int EB  = (E + EPB - 1) / EPB;
    const int nw  = (n + 3) / 4;
    const int nl  = (n + 63) / 64;
    const int w1  = (16384 + 255) / 256;
    const int w4  = (4 * 16384 + 255) / 256;

    detect_kernel<<<1, 256, 0, stream>>>((const unsigned*)eix, flag);
    convert_kernel<<<nbE, 256, 0, stream>>>(eix, E, flag, src32, dst32);
    hipMemsetAsync(btot, 0, 256 * 4, stream);
    p1_count<<<EB, 256, 0, stream>>>(dst32, E, btot, NBINS);
    p1_scan<<<1, 256, 0, stream>>>(btot, bbase, bcur, rowptr, NBINS, n, E);
    p1_scatter<<<EB, 256, 0, stream>>>(src32, dst32, E, bcur, ssrc, sdst);
    p2_build<<<NBINS, 256, 0, stream>>>(sdst, ssrc, bbase, rowptr, csr, n);

    wtrans_kernel<<<w1, 256, 0, stream>>>(Wn, wn_t, 1);
    wtrans_kernel<<<w4, 256, 0, stream>>>(WQ, wq_t, 4);
    wtrans_kernel<<<w4, 256, 0, stream>>>(WK, wk_t, 4);
    wtrans_kernel<<<w4, 256, 0, stream>>>(WV, wv_t, 4);
    wtrans_kernel<<<w4, 256, 0, stream>>>(WO, wo_t, 4);
    wtrans_kernel<<<w1, 256, 0, stream>>>(Wout, wout_t, 1);

    // hb = bf16(x @ Wn + bn)
    lin_kernel<true, false, false, true><<<nl, 256, 0, stream>>>(
        x, wn_t, bn, nullptr, nullptr, nullptr, nullptr, hb, n);

    for (int l = 0; l < L; ++l) {
        lin3_kernel<<<nl, 256, 0, stream>>>(
            hb, wq_t + (size_t)l * 16384, wk_t + (size_t)l * 16384, wv_t + (size_t)l * 16384,
            bQ + l * HD, bK + l * HD, bV + l * HD, qb, kb, vb, n);
        attn_kernel<<<nw, 256, 0, stream>>>(qb, kb, vb, rowptr, csr, mb, n);
        // hb = bf16(LN(hb + mb@WO + bO))  (in-place residual: rows wave-private)
        lin_kernel<false, true, false, true><<<nl, 256, 0, stream>>>(
            mb, wo_t + (size_t)l * 16384, bO + l * HD, lng + l * HD, lnb + l * HD,
            hb, nullptr, hb, n);
    }
    lin_kernel<false, false, true, false><<<nl, 256, 0, stream>>>(
        hb, wout_t, bout, nullptr, nullptr, nullptr, (float*)d_out, nullptr, n);
}

// Round 4
// 852.237 us; speedup vs baseline: 2.6897x; 1.4290x over previous
//
#include <hip/hip_runtime.h>
#include <cstdint>
#include <cstddef>

#define HD 128

typedef __attribute__((ext_vector_type(8))) short bf16x8;
typedef __attribute__((ext_vector_type(8))) unsigned short u16x8;
typedef __attribute__((ext_vector_type(4))) float f32x4;

__device__ __forceinline__ unsigned short f2bf(float x) {
    unsigned int b = __float_as_uint(x);
    b += 0x7FFFu + ((b >> 16) & 1u);
    return (unsigned short)(b >> 16);
}
__device__ __forceinline__ float bf2f(unsigned short u) {
    return __uint_as_float(((unsigned int)u) << 16);
}

// ---------------- edge-index handling ----------------
// flag=1 -> int32 data, flag=0 -> int64
__global__ void detect_kernel(const unsigned* __restrict__ w, int* __restrict__ flag) {
    if (threadIdx.x == 0) *flag = 0;
    __syncthreads();
    unsigned v = w[2 * threadIdx.x + 1];
    if (v != 0u) atomicOr(flag, 1);
}

__device__ __forceinline__ int eload(const void* raw, int is32, size_t i) {
    return is32 ? ((const int*)raw)[i] : (int)((const long long*)raw)[i];
}

// ---------------- CSR build: two-level bucket sort (bin = dst>>9) ----------------
#define EPB 4096

__global__ __launch_bounds__(256) void p1_count(const void* __restrict__ raw,
                                                const int* __restrict__ flag, int E,
                                                int* __restrict__ tot, int nbins) {
    __shared__ int h[256];
    const int tid = threadIdx.x;
    const int is32 = *flag;
    h[tid] = 0;
    __syncthreads();
    const int base = blockIdx.x * EPB;
    const int lim = min(E, base + EPB);
    for (int i = base + tid; i < lim; i += 256) atomicAdd(&h[eload(raw, is32, (size_t)E + i) >> 9], 1);
    __syncthreads();
    if (tid < nbins && h[tid]) atomicAdd(&tot[tid], h[tid]);
}

__global__ __launch_bounds__(256) void p1_scan(const int* __restrict__ tot,
                                               int* __restrict__ base, int* __restrict__ cursor,
                                               int* __restrict__ rowptr, int nbins, int n, int E) {
    __shared__ int s[256];
    const int tid = threadIdx.x;
    const int v = (tid < nbins) ? tot[tid] : 0;
    s[tid] = v;
    __syncthreads();
#pragma unroll
    for (int o = 1; o < 256; o <<= 1) {
        int t = (tid >= o) ? s[tid - o] : 0;
        __syncthreads();
        s[tid] += t;
        __syncthreads();
    }
    if (tid < nbins) {
        base[tid] = s[tid] - v;
        cursor[tid] = s[tid] - v;
    }
    if (tid == 0) {
        base[nbins] = E;
        rowptr[n] = E;
    }
}

__global__ __launch_bounds__(256) void p1_scatter(const void* __restrict__ raw,
                                                  const int* __restrict__ flag, int E,
                                                  int* __restrict__ cursor,
                                                  int* __restrict__ ssrc, int* __restrict__ sdst) {
    __shared__ int h[256];
    __shared__ int cur[256];
    const int tid = threadIdx.x;
    const int is32 = *flag;
    h[tid] = 0;
    __syncthreads();
    const int base = blockIdx.x * EPB;
    const int lim = min(E, base + EPB);
    for (int i = base + tid; i < lim; i += 256) atomicAdd(&h[eload(raw, is32, (size_t)E + i) >> 9], 1);
    __syncthreads();
    if (h[tid]) cur[tid] = atomicAdd(&cursor[tid], h[tid]);
    __syncthreads();
    for (int i = base + tid; i < lim; i += 256) {
        const int d = eload(raw, is32, (size_t)E + i);
        const int pos = atomicAdd(&cur[d >> 9], 1);
        sdst[pos] = d;
        ssrc[pos] = eload(raw, is32, i);
    }
}

__global__ __launch_bounds__(256) void p2_build(const int* __restrict__ sdst,
                                                const int* __restrict__ ssrc,
                                                const int* __restrict__ bucket_base,
                                                int* __restrict__ rowptr, int* __restrict__ csr,
                                                int n) {
    const int bin = blockIdx.x;
    const int b0 = bucket_base[bin], b1 = bucket_base[bin + 1];
    __shared__ int cnt[512];
    __shared__ int ps[256];
    __shared__ int cur[512];
    const int tid = threadIdx.x;
    cnt[tid] = 0;
    cnt[tid + 256] = 0;
    __syncthreads();
    for (int e = b0 + tid; e < b1; e += 256) atomicAdd(&cnt[sdst[e] & 511], 1);
    __syncthreads();
    const int a = cnt[2 * tid], b = cnt[2 * tid + 1];
    ps[tid] = a + b;
    __syncthreads();
#pragma unroll
    for (int o = 1; o < 256; o <<= 1) {
        int t = (tid >= o) ? ps[tid - o] : 0;
        __syncthreads();
        ps[tid] += t;
        __syncthreads();
    }
    const int e0 = ps[tid] - (a + b);
    const int e1 = e0 + a;
    const int v0 = bin * 512 + 2 * tid;
    if (v0 < n) rowptr[v0] = b0 + e0;
    if (v0 + 1 < n) rowptr[v0 + 1] = b0 + e1;
    cur[2 * tid] = b0 + e0;
    cur[2 * tid + 1] = b0 + e1;
    __syncthreads();
    for (int e = b0 + tid; e < b1; e += 256) {
        const int pos = atomicAdd(&cur[sdst[e] & 511], 1);
        csr[pos] = ssrc[e];
    }
}

// ---------------- all-weights transpose+convert ----------------
// wt layout (by mat index m): 0 = Wn; for layer l: 1+3l = WQ[l], 2+3l = WK[l], 3+3l = WV[l]
// (l=0..3 -> m=1..12); 13+l = WO[l]; 17 = Wout.   wt[m][c][k] = W_m[k][c] in bf16.
struct WPtrs { const float* p[6]; };

__global__ void wtrans_all(WPtrs ws, unsigned short* __restrict__ dst) {
    int i = blockIdx.x * 256 + threadIdx.x;  // over 18*16384
    if (i >= 18 * 16384) return;
    int m = i >> 14;
    int r = i & 16383;
    int k = r >> 7, c = r & 127;
    const float* s;
    int off;
    if (m == 0)      { s = ws.p[0]; off = 0; }
    else if (m < 13) { int q = (m - 1) % 3, l = (m - 1) / 3; s = ws.p[1 + q]; off = l; }
    else if (m < 17) { s = ws.p[4]; off = m - 13; }
    else             { s = ws.p[5]; off = 0; }
    dst[(size_t)m * 16384 + (size_t)c * HD + k] = f2bf(s[(size_t)off * 16384 + r]);
}

// ---------------- MFMA linear (LDS-staged weights), wave = 16 rows x 128 cols ----------------
#define WLSTRIDE 132  // shorts; ds_read_b128 start banks (2t+4g)%32 spread evenly

__device__ __forceinline__ void stage_w(const unsigned short* __restrict__ Wt,
                                        unsigned short* __restrict__ wl, int tid) {
#pragma unroll
    for (int s = 0; s < 8; ++s) {
        const int slot = s * 256 + tid;
        const int row = slot >> 4, c8 = (slot & 15) << 3;
        *(u16x8*)&wl[row * WLSTRIDE + c8] = *(const u16x8*)&Wt[(size_t)row * HD + c8];
    }
}

template <bool AIN_F32, bool RESID_LN, bool OUT_F32, bool OUT_BF>
__global__ __launch_bounds__(256) void lin_lds(
    const void* __restrict__ Xin, const unsigned short* __restrict__ Wt,
    const float* __restrict__ bias,
    const float* __restrict__ lng, const float* __restrict__ lnb,
    const unsigned short* __restrict__ Rb, float* __restrict__ Yf,
    unsigned short* __restrict__ Yb, int n) {
    __shared__ unsigned short wl[128 * WLSTRIDE];
    const int tid = threadIdx.x;
    const int w = tid >> 6;
    const int lane = tid & 63;
    const int t = lane & 15, g = lane >> 4;
    const int waveBase = blockIdx.x * 64 + w * 16;
    const int arow = waveBase + t;
    const bool rowOK = arow < n;

    stage_w(Wt, wl, tid);

    bf16x8 af[4];
#pragma unroll
    for (int ks = 0; ks < 4; ++ks) {
        const int k = ks * 32 + g * 8;
        bf16x8 a = (bf16x8){0, 0, 0, 0, 0, 0, 0, 0};
        if (rowOK) {
            if (AIN_F32) {
                const float* Xf = (const float*)Xin;
                float4 x0 = *(const float4*)&Xf[(size_t)arow * HD + k];
                float4 x1 = *(const float4*)&Xf[(size_t)arow * HD + k + 4];
                a[0] = (short)f2bf(x0.x); a[1] = (short)f2bf(x0.y);
                a[2] = (short)f2bf(x0.z); a[3] = (short)f2bf(x0.w);
                a[4] = (short)f2bf(x1.x); a[5] = (short)f2bf(x1.y);
                a[6] = (short)f2bf(x1.z); a[7] = (short)f2bf(x1.w);
            } else {
                const unsigned short* Xb = (const unsigned short*)Xin;
                a = *(const bf16x8*)&Xb[(size_t)arow * HD + k];
            }
        }
        af[ks] = a;
    }

    __syncthreads();

    f32x4 acc[8];
#pragma unroll
    for (int nf = 0; nf < 8; ++nf) acc[nf] = (f32x4){0.f, 0.f, 0.f, 0.f};
#pragma unroll
    for (int ks = 0; ks < 4; ++ks) {
        const int k = ks * 32 + g * 8;
#pragma unroll
        for (int nf = 0; nf < 8; ++nf) {
            bf16x8 b = *(const bf16x8*)&wl[(nf * 16 + t) * WLSTRIDE + k];
            acc[nf] = __builtin_amdgcn_mfma_f32_16x16x32_bf16(af[ks], b, acc[nf], 0, 0, 0);
        }
    }

    float v[8][4];
#pragma unroll
    for (int nf = 0; nf < 8; ++nf) {
        const int col = nf * 16 + t;
        const float bv = bias[col];
#pragma unroll
        for (int r = 0; r < 4; ++r) {
            float x = acc[nf][r] + bv;
            if (RESID_LN) {
                const int row = waveBase + g * 4 + r;
                if (row < n) x += bf2f(Rb[(size_t)row * HD + col]);
            }
            v[nf][r] = x;
        }
    }

    if (RESID_LN) {
#pragma unroll
        for (int r = 0; r < 4; ++r) {
            float s = 0.f, sq = 0.f;
#pragma unroll
            for (int nf = 0; nf < 8; ++nf) { s += v[nf][r]; sq += v[nf][r] * v[nf][r]; }
#pragma unroll
            for (int mask = 1; mask < 16; mask <<= 1) {
                s += __shfl_xor(s, mask, 64);
                sq += __shfl_xor(sq, mask, 64);
            }
            const float mu = s * (1.f / 128.f);
            const float var = sq * (1.f / 128.f) - mu * mu;
            const float inv = rsqrtf(var + 1e-5f);
#pragma unroll
            for (int nf = 0; nf < 8; ++nf) {
                const int col = nf * 16 + t;
                v[nf][r] = (v[nf][r] - mu) * inv * lng[col] + lnb[col];
            }
        }
    }

#pragma unroll
    for (int r = 0; r < 4; ++r) {
        const int row = waveBase + g * 4 + r;
        if (row < n) {
#pragma unroll
            for (int nf = 0; nf < 8; ++nf) {
                const int col = nf * 16 + t;
                if (OUT_F32) Yf[(size_t)row * HD + col] = v[nf][r];
                if (OUT_BF) Yb[(size_t)row * HD + col] = f2bf(v[nf][r]);
            }
        }
    }
}

// ---------------- fused QKV (LDS-staged, 3 consecutive matrices) ----------------
// Wt3 = wt + (1+3l)*16384: [WQ | WK | WV] contiguous.
// mat0 -> Q (stride 128), mat1 -> K (kv, stride 256, off 0), mat2 -> V (kv, stride 256, off 128)
__global__ __launch_bounds__(256) void lin3_lds(
    const unsigned short* __restrict__ Xb, const unsigned short* __restrict__ Wt3,
    const float* __restrict__ b0, const float* __restrict__ b1, const float* __restrict__ b2,
    unsigned short* __restrict__ Qb, unsigned short* __restrict__ KV, int n) {
    __shared__ unsigned short wl[128 * WLSTRIDE];
    const int tid = threadIdx.x;
    const int w = tid >> 6;
    const int lane = tid & 63;
    const int t = lane & 15, g = lane >> 4;
    const int waveBase = blockIdx.x * 64 + w * 16;
    const int arow = waveBase + t;
    const bool rowOK = arow < n;

    bf16x8 af[4];
#pragma unroll
    for (int ks = 0; ks < 4; ++ks) {
        bf16x8 a = (bf16x8){0, 0, 0, 0, 0, 0, 0, 0};
        if (rowOK) a = *(const bf16x8*)&Xb[(size_t)arow * HD + ks * 32 + g * 8];
        af[ks] = a;
    }

    const float* bs[3] = {b0, b1, b2};

#pragma unroll
    for (int mat = 0; mat < 3; ++mat) {
        if (mat) __syncthreads();
        stage_w(Wt3 + (size_t)mat * 16384, wl, tid);
        __syncthreads();

        f32x4 acc[8];
#pragma unroll
        for (int nf = 0; nf < 8; ++nf) acc[nf] = (f32x4){0.f, 0.f, 0.f, 0.f};
#pragma unroll
        for (int ks = 0; ks < 4; ++ks) {
            const int k = ks * 32 + g * 8;
#pragma unroll
            for (int nf = 0; nf < 8; ++nf) {
                bf16x8 b = *(const bf16x8*)&wl[(nf * 16 + t) * WLSTRIDE + k];
                acc[nf] = __builtin_amdgcn_mfma_f32_16x16x32_bf16(af[ks], b, acc[nf], 0, 0, 0);
            }
        }

        unsigned short* outp = (mat == 0) ? Qb : KV;
        const int rs = (mat == 0) ? 128 : 256;
        const int co = (mat == 2) ? 128 : 0;
#pragma unroll
        for (int r = 0; r < 4; ++r) {
            const int row = waveBase + g * 4 + r;
            if (row < n) {
#pragma unroll
                for (int nf = 0; nf < 8; ++nf) {
                    const int col = nf * 16 + t;
                    outp[(size_t)row * rs + co + col] = f2bf(acc[nf][r] + bs[mat][col]);
                }
            }
        }
    }
}

// ---------------- fused edge attention: no-max softmax, interleaved KV ----------------
__global__ __launch_bounds__(256) void attn_kernel(
    const unsigned short* __restrict__ Qb, const unsigned short* __restrict__ KV,
    const int* __restrict__ rowptr, const int* __restrict__ csr,
    unsigned short* __restrict__ Mb, int n) {
    const int d = (blockIdx.x * 256 + threadIdx.x) >> 6;
    if (d >= n) return;
    const int lane = threadIdx.x & 63;
    const int t = lane & 15, g = lane >> 4;
    const int beg = rowptr[d], end = rowptr[d + 1];

    const float scale = 0.08838834764831845f;  // 1/sqrt(128)
    float qv[8];
    {
        u16x8 qu = *(const u16x8*)&Qb[(size_t)d * HD + t * 8];
#pragma unroll
        for (int j = 0; j < 8; ++j) qv[j] = bf2f(qu[j]) * scale;
    }
    float ss = 0.f;
    float acc[8];
#pragma unroll
    for (int j = 0; j < 8; ++j) acc[j] = 0.f;

    const int nit = (end - beg + 3) >> 2;
    for (int it = 0; it < nit; ++it) {
        const int idx = beg + it * 4 + g;
        const bool act = idx < end;
        const int s = act ? csr[idx] : 0;
        const unsigned short* kvp = &KV[(size_t)s * 256 + t * 8];
        u16x8 ku = *(const u16x8*)kvp;
        u16x8 vu = *(const u16x8*)(kvp + 128);
        float p = 0.f;
#pragma unroll
        for (int j = 0; j < 8; ++j) p += bf2f(ku[j]) * qv[j];
#pragma unroll
        for (int mask = 1; mask < 16; mask <<= 1) p += __shfl_xor(p, mask, 64);
        const float e = act ? __expf(p) : 0.f;  // LN-scale scores: no max-sub needed in fp32
        ss += e;
#pragma unroll
        for (int j = 0; j < 8; ++j) acc[j] = fmaf(e, bf2f(vu[j]), acc[j]);
    }

#pragma unroll
    for (int mask = 16; mask <= 32; mask <<= 1) {
        ss += __shfl_xor(ss, mask, 64);
#pragma unroll
        for (int j = 0; j < 8; ++j) acc[j] += __shfl_xor(acc[j], mask, 64);
    }

    const float inv = (end > beg) ? 1.f / ss : 0.f;
    if (g == 0) {
        u16x8 o;
#pragma unroll
        for (int j = 0; j < 8; ++j) o[j] = f2bf(acc[j] * inv);
        *(u16x8*)&Mb[(size_t)d * HD + t * 8] = o;
    }
}

// ---------------- launch ----------------
extern "C" void kernel_launch(void* const* d_in, const int* in_sizes, int n_in,
                              void* d_out, int out_size, void* d_ws, size_t ws_size,
                              hipStream_t stream) {
    const float* x    = (const float*)d_in[0];
    const void*  eix  = d_in[1];
    const float* Wn   = (const float*)d_in[2];
    const float* bn   = (const float*)d_in[3];
    const float* WQ   = (const float*)d_in[4];
    const float* bQ   = (const float*)d_in[5];
    const float* WK   = (const float*)d_in[6];
    const float* bK   = (const float*)d_in[7];
    const float* WV   = (const float*)d_in[8];
    const float* bV   = (const float*)d_in[9];
    const float* WO   = (const float*)d_in[10];
    const float* bO   = (const float*)d_in[11];
    const float* lng  = (const float*)d_in[12];
    const float* lnb  = (const float*)d_in[13];
    const float* Wout = (const float*)d_in[14];
    const float* bout = (const float*)d_in[15];

    const int n = in_sizes[0] / HD;
    const int E = in_sizes[1] / 2;
    const int L = 4;
    const int NBINS = (n + 511) >> 9;

    char* p = (char*)d_ws;
    auto alloc = [&](size_t bytes) -> void* {
        void* r = (void*)p;
        p += (bytes + 255) & ~(size_t)255;
        return r;
    };
    unsigned short* hb = (unsigned short*)alloc((size_t)n * HD * 2);
    unsigned short* qb = (unsigned short*)alloc((size_t)n * HD * 2);
    unsigned short* kv = (unsigned short*)alloc((size_t)n * HD * 4);  // interleaved K|V
    unsigned short* mb = (unsigned short*)alloc((size_t)n * HD * 2);
    int* ssrc   = (int*)alloc((size_t)E * 4);
    int* sdst   = (int*)alloc((size_t)E * 4);
    int* csr    = (int*)alloc((size_t)E * 4);
    int* rowptr = (int*)alloc((size_t)(n + 1) * 4);
    int* btot   = (int*)alloc(256 * 4);
    int* bbase  = (int*)alloc(257 * 4);
    int* bcur   = (int*)alloc(256 * 4);
    int* flag   = (int*)alloc(256);
    unsigned short* wt = (unsigned short*)alloc(18 * 16384 * 2);

    const int EB = (E + EPB - 1) / EPB;
    const int nw = (n + 3) / 4;
    const int nl = (n + 63) / 64;

    detect_kernel<<<1, 256, 0, stream>>>((const unsigned*)eix, flag);
    hipMemsetAsync(btot, 0, 256 * 4, stream);
    p1_count<<<EB, 256, 0, stream>>>(eix, flag, E, btot, NBINS);
    p1_scan<<<1, 256, 0, stream>>>(btot, bbase, bcur, rowptr, NBINS, n, E);
    p1_scatter<<<EB, 256, 0, stream>>>(eix, flag, E, bcur, ssrc, sdst);
    p2_build<<<NBINS, 256, 0, stream>>>(sdst, ssrc, bbase, rowptr, csr, n);

    WPtrs wp;
    wp.p[0] = Wn; wp.p[1] = WQ; wp.p[2] = WK; wp.p[3] = WV; wp.p[4] = WO; wp.p[5] = Wout;
    wtrans_all<<<(18 * 16384 + 255) / 256, 256, 0, stream>>>(wp, wt);

    // hb = bf16(x @ Wn + bn)
    lin_lds<true, false, false, true><<<nl, 256, 0, stream>>>(
        x, wt, bn, nullptr, nullptr, nullptr, nullptr, hb, n);

    for (int l = 0; l < L; ++l) {
        lin3_lds<<<nl, 256, 0, stream>>>(
            hb, wt + (size_t)(1 + 3 * l) * 16384, bQ + l * HD, bK + l * HD, bV + l * HD,
            qb, kv, n);
        attn_kernel<<<nw, 256, 0, stream>>>(qb, kv, rowptr, csr, mb, n);
        lin_lds<false, true, false, true><<<nl, 256, 0, stream>>>(
            mb, wt + (size_t)(13 + l) * 16384, bO + l * HD, lng + l * HD, lnb + l * HD,
            hb, nullptr, hb, n);
    }
    lin_lds<false, false, true, false><<<nl, 256, 0, stream>>>(
        hb, wt + (size_t)17 * 16384, bout, nullptr, nullptr, nullptr, (float*)d_out, nullptr, n);
}

// Round 6
// 839.074 us; speedup vs baseline: 2.7319x; 1.0157x over previous
//
#include <hip/hip_runtime.h>
#include <cstdint>
#include <cstddef>

#define HD 128

typedef __attribute__((ext_vector_type(8))) short bf16x8;
typedef __attribute__((ext_vector_type(8))) unsigned short u16x8;
typedef __attribute__((ext_vector_type(4))) float f32x4;

__device__ __forceinline__ unsigned short f2bf(float x) {
    unsigned int b = __float_as_uint(x);
    b += 0x7FFFu + ((b >> 16) & 1u);
    return (unsigned short)(b >> 16);
}
__device__ __forceinline__ float bf2f(unsigned short u) {
    return __uint_as_float(((unsigned int)u) << 16);
}

// ---------------- edge-index handling ----------------
// flag=1 -> int32 data, flag=0 -> int64
__global__ void detect_kernel(const unsigned* __restrict__ w, int* __restrict__ flag) {
    if (threadIdx.x == 0) *flag = 0;
    __syncthreads();
    unsigned v = w[2 * threadIdx.x + 1];
    if (v != 0u) atomicOr(flag, 1);
}

__device__ __forceinline__ int eload(const void* raw, int is32, size_t i) {
    return is32 ? ((const int*)raw)[i] : (int)((const long long*)raw)[i];
}

// ---------------- CSR build: two-level bucket sort (bin = dst>>9) ----------------
#define EPB 4096

__global__ __launch_bounds__(256) void p1_count(const void* __restrict__ raw,
                                                const int* __restrict__ flag, int E,
                                                int* __restrict__ tot, int nbins) {
    __shared__ int h[256];
    const int tid = threadIdx.x;
    const int is32 = *flag;
    h[tid] = 0;
    __syncthreads();
    const int base = blockIdx.x * EPB;
    const int lim = min(E, base + EPB);
    for (int i = base + tid; i < lim; i += 256) atomicAdd(&h[eload(raw, is32, (size_t)E + i) >> 9], 1);
    __syncthreads();
    if (tid < nbins && h[tid]) atomicAdd(&tot[tid], h[tid]);
}

__global__ __launch_bounds__(256) void p1_scan(const int* __restrict__ tot,
                                               int* __restrict__ base, int* __restrict__ cursor,
                                               int* __restrict__ rowptr, int nbins, int n, int E) {
    __shared__ int s[256];
    const int tid = threadIdx.x;
    const int v = (tid < nbins) ? tot[tid] : 0;
    s[tid] = v;
    __syncthreads();
#pragma unroll
    for (int o = 1; o < 256; o <<= 1) {
        int t = (tid >= o) ? s[tid - o] : 0;
        __syncthreads();
        s[tid] += t;
        __syncthreads();
    }
    if (tid < nbins) {
        base[tid] = s[tid] - v;
        cursor[tid] = s[tid] - v;
    }
    if (tid == 0) {
        base[nbins] = E;
        rowptr[n] = E;
    }
}

__global__ __launch_bounds__(256) void p1_scatter(const void* __restrict__ raw,
                                                  const int* __restrict__ flag, int E,
                                                  int* __restrict__ cursor,
                                                  int* __restrict__ ssrc, int* __restrict__ sdst) {
    __shared__ int h[256];
    __shared__ int cur[256];
    const int tid = threadIdx.x;
    const int is32 = *flag;
    h[tid] = 0;
    __syncthreads();
    const int base = blockIdx.x * EPB;
    const int lim = min(E, base + EPB);
    for (int i = base + tid; i < lim; i += 256) atomicAdd(&h[eload(raw, is32, (size_t)E + i) >> 9], 1);
    __syncthreads();
    if (h[tid]) cur[tid] = atomicAdd(&cursor[tid], h[tid]);
    __syncthreads();
    for (int i = base + tid; i < lim; i += 256) {
        const int d = eload(raw, is32, (size_t)E + i);
        const int pos = atomicAdd(&cur[d >> 9], 1);
        sdst[pos] = d;
        ssrc[pos] = eload(raw, is32, i);
    }
}

__global__ __launch_bounds__(256) void p2_build(const int* __restrict__ sdst,
                                                const int* __restrict__ ssrc,
                                                const int* __restrict__ bucket_base,
                                                int* __restrict__ rowptr, int* __restrict__ csr,
                                                int n) {
    const int bin = blockIdx.x;
    const int b0 = bucket_base[bin], b1 = bucket_base[bin + 1];
    __shared__ int cnt[512];
    __shared__ int ps[256];
    __shared__ int cur[512];
    const int tid = threadIdx.x;
    cnt[tid] = 0;
    cnt[tid + 256] = 0;
    __syncthreads();
    for (int e = b0 + tid; e < b1; e += 256) atomicAdd(&cnt[sdst[e] & 511], 1);
    __syncthreads();
    const int a = cnt[2 * tid], b = cnt[2 * tid + 1];
    ps[tid] = a + b;
    __syncthreads();
#pragma unroll
    for (int o = 1; o < 256; o <<= 1) {
        int t = (tid >= o) ? ps[tid - o] : 0;
        __syncthreads();
        ps[tid] += t;
        __syncthreads();
    }
    const int e0 = ps[tid] - (a + b);
    const int e1 = e0 + a;
    const int v0 = bin * 512 + 2 * tid;
    if (v0 < n) rowptr[v0] = b0 + e0;
    if (v0 + 1 < n) rowptr[v0 + 1] = b0 + e1;
    cur[2 * tid] = b0 + e0;
    cur[2 * tid + 1] = b0 + e1;
    __syncthreads();
    for (int e = b0 + tid; e < b1; e += 256) {
        const int pos = atomicAdd(&cur[sdst[e] & 511], 1);
        csr[pos] = ssrc[e];
    }
}

// ---------------- all-weights transpose+convert ----------------
// wt layout (by mat index m): 0 = Wn; layer l: 1+3l = WQ[l], 2+3l = WK[l], 3+3l = WV[l];
// 13+l = WO[l]; 17 = Wout.   wt[m][c][k] = W_m[k][c] in bf16.
struct WPtrs { const float* p[6]; };

__global__ void wtrans_all(WPtrs ws, unsigned short* __restrict__ dst) {
    int i = blockIdx.x * 256 + threadIdx.x;  // over 18*16384
    if (i >= 18 * 16384) return;
    int m = i >> 14;
    int r = i & 16383;
    int k = r >> 7, c = r & 127;
    const float* s;
    int off;
    if (m == 0)      { s = ws.p[0]; off = 0; }
    else if (m < 13) { int q = (m - 1) % 3, l = (m - 1) / 3; s = ws.p[1 + q]; off = l; }
    else if (m < 17) { s = ws.p[4]; off = m - 13; }
    else             { s = ws.p[5]; off = 0; }
    dst[(size_t)m * 16384 + (size_t)c * HD + k] = f2bf(s[(size_t)off * 16384 + r]);
}

// ---------------- MFMA linear (LDS-staged weights), wave = 16 rows x 128 cols ----------------
#define WLSTRIDE 132

__device__ __forceinline__ void stage_w(const unsigned short* __restrict__ Wt,
                                        unsigned short* __restrict__ wl, int tid) {
#pragma unroll
    for (int s = 0; s < 8; ++s) {
        const int slot = s * 256 + tid;
        const int row = slot >> 4, c8 = (slot & 15) << 3;
        *(u16x8*)&wl[row * WLSTRIDE + c8] = *(const u16x8*)&Wt[(size_t)row * HD + c8];
    }
}

template <bool AIN_F32, bool RESID_LN, bool OUT_F32, bool OUT_BF>
__global__ __launch_bounds__(256) void lin_lds(
    const void* __restrict__ Xin, const unsigned short* __restrict__ Wt,
    const float* __restrict__ bias,
    const float* __restrict__ lng, const float* __restrict__ lnb,
    const unsigned short* __restrict__ Rb, float* __restrict__ Yf,
    unsigned short* __restrict__ Yb, int n) {
    __shared__ unsigned short wl[128 * WLSTRIDE];
    const int tid = threadIdx.x;
    const int w = tid >> 6;
    const int lane = tid & 63;
    const int t = lane & 15, g = lane >> 4;
    const int waveBase = blockIdx.x * 64 + w * 16;
    const int arow = waveBase + t;
    const bool rowOK = arow < n;

    stage_w(Wt, wl, tid);

    bf16x8 af[4];
#pragma unroll
    for (int ks = 0; ks < 4; ++ks) {
        const int k = ks * 32 + g * 8;
        bf16x8 a = (bf16x8){0, 0, 0, 0, 0, 0, 0, 0};
        if (rowOK) {
            if (AIN_F32) {
                const float* Xf = (const float*)Xin;
                float4 x0 = *(const float4*)&Xf[(size_t)arow * HD + k];
                float4 x1 = *(const float4*)&Xf[(size_t)arow * HD + k + 4];
                a[0] = (short)f2bf(x0.x); a[1] = (short)f2bf(x0.y);
                a[2] = (short)f2bf(x0.z); a[3] = (short)f2bf(x0.w);
                a[4] = (short)f2bf(x1.x); a[5] = (short)f2bf(x1.y);
                a[6] = (short)f2bf(x1.z); a[7] = (short)f2bf(x1.w);
            } else {
                const unsigned short* Xb = (const unsigned short*)Xin;
                a = *(const bf16x8*)&Xb[(size_t)arow * HD + k];
            }
        }
        af[ks] = a;
    }

    __syncthreads();

    f32x4 acc[8];
#pragma unroll
    for (int nf = 0; nf < 8; ++nf) acc[nf] = (f32x4){0.f, 0.f, 0.f, 0.f};
#pragma unroll
    for (int ks = 0; ks < 4; ++ks) {
        const int k = ks * 32 + g * 8;
#pragma unroll
        for (int nf = 0; nf < 8; ++nf) {
            bf16x8 b = *(const bf16x8*)&wl[(nf * 16 + t) * WLSTRIDE + k];
            acc[nf] = __builtin_amdgcn_mfma_f32_16x16x32_bf16(af[ks], b, acc[nf], 0, 0, 0);
        }
    }

    float v[8][4];
#pragma unroll
    for (int nf = 0; nf < 8; ++nf) {
        const int col = nf * 16 + t;
        const float bv = bias[col];
#pragma unroll
        for (int r = 0; r < 4; ++r) {
            float x = acc[nf][r] + bv;
            if (RESID_LN) {
                const int row = waveBase + g * 4 + r;
                if (row < n) x += bf2f(Rb[(size_t)row * HD + col]);
            }
            v[nf][r] = x;
        }
    }

    if (RESID_LN) {
#pragma unroll
        for (int r = 0; r < 4; ++r) {
            float s = 0.f, sq = 0.f;
#pragma unroll
            for (int nf = 0; nf < 8; ++nf) { s += v[nf][r]; sq += v[nf][r] * v[nf][r]; }
#pragma unroll
            for (int mask = 1; mask < 16; mask <<= 1) {
                s += __shfl_xor(s, mask, 64);
                sq += __shfl_xor(sq, mask, 64);
            }
            const float mu = s * (1.f / 128.f);
            const float var = sq * (1.f / 128.f) - mu * mu;
            const float inv = rsqrtf(var + 1e-5f);
#pragma unroll
            for (int nf = 0; nf < 8; ++nf) {
                const int col = nf * 16 + t;
                v[nf][r] = (v[nf][r] - mu) * inv * lng[col] + lnb[col];
            }
        }
    }

#pragma unroll
    for (int r = 0; r < 4; ++r) {
        const int row = waveBase + g * 4 + r;
        if (row < n) {
#pragma unroll
            for (int nf = 0; nf < 8; ++nf) {
                const int col = nf * 16 + t;
                if (OUT_F32) Yf[(size_t)row * HD + col] = v[nf][r];
                if (OUT_BF) Yb[(size_t)row * HD + col] = f2bf(v[nf][r]);
            }
        }
    }
}

// ---------------- fused QKV (LDS-staged, 3 consecutive matrices) ----------------
// mat0 -> Q bf16 [n][128]; mat1 -> K into KV[row][0..127]; mat2 -> V into KV[row][128..255]
__global__ __launch_bounds__(256) void lin3_lds(
    const unsigned short* __restrict__ Xb, const unsigned short* __restrict__ Wt3,
    const float* __restrict__ b0, const float* __restrict__ b1, const float* __restrict__ b2,
    unsigned short* __restrict__ Qb, unsigned short* __restrict__ KV, int n) {
    __shared__ unsigned short wl[128 * WLSTRIDE];
    const int tid = threadIdx.x;
    const int w = tid >> 6;
    const int lane = tid & 63;
    const int t = lane & 15, g = lane >> 4;
    const int waveBase = blockIdx.x * 64 + w * 16;
    const int arow = waveBase + t;
    const bool rowOK = arow < n;

    bf16x8 af[4];
#pragma unroll
    for (int ks = 0; ks < 4; ++ks) {
        bf16x8 a = (bf16x8){0, 0, 0, 0, 0, 0, 0, 0};
        if (rowOK) a = *(const bf16x8*)&Xb[(size_t)arow * HD + ks * 32 + g * 8];
        af[ks] = a;
    }

    const float* bs[3] = {b0, b1, b2};

#pragma unroll
    for (int mat = 0; mat < 3; ++mat) {
        if (mat) __syncthreads();
        stage_w(Wt3 + (size_t)mat * 16384, wl, tid);
        __syncthreads();

        f32x4 acc[8];
#pragma unroll
        for (int nf = 0; nf < 8; ++nf) acc[nf] = (f32x4){0.f, 0.f, 0.f, 0.f};
#pragma unroll
        for (int ks = 0; ks < 4; ++ks) {
            const int k = ks * 32 + g * 8;
#pragma unroll
            for (int nf = 0; nf < 8; ++nf) {
                bf16x8 b = *(const bf16x8*)&wl[(nf * 16 + t) * WLSTRIDE + k];
                acc[nf] = __builtin_amdgcn_mfma_f32_16x16x32_bf16(af[ks], b, acc[nf], 0, 0, 0);
            }
        }

        unsigned short* outp = (mat == 0) ? Qb : KV;
        const int rs = (mat == 0) ? 128 : 256;
        const int co = (mat == 2) ? 128 : 0;
#pragma unroll
        for (int r = 0; r < 4; ++r) {
            const int row = waveBase + g * 4 + r;
            if (row < n) {
#pragma unroll
                for (int nf = 0; nf < 8; ++nf) {
                    const int col = nf * 16 + t;
                    outp[(size_t)row * rs + co + col] = f2bf(acc[nf][r] + bs[mat][col]);
                }
            }
        }
    }
}

// ---------------- fused edge attention: no-max softmax, bf16 KV, 8-edge ILP ----------------
// 8 lanes per edge (t=lane&7 handles 16 elems), 8 edges in flight (g=lane>>3)
__global__ __launch_bounds__(256) void attn_kernel(
    const unsigned short* __restrict__ Qb, const unsigned short* __restrict__ KV,
    const int* __restrict__ rowptr, const int* __restrict__ csr,
    unsigned short* __restrict__ Mb, int n) {
    const int d = (blockIdx.x * 256 + threadIdx.x) >> 6;
    if (d >= n) return;
    const int lane = threadIdx.x & 63;
    const int t = lane & 7, g = lane >> 3;
    const int beg = rowptr[d], end = rowptr[d + 1];

    const float scale = 0.08838834764831845f;  // 1/sqrt(128)
    float qv[16];
    {
        u16x8 q0 = *(const u16x8*)&Qb[(size_t)d * HD + t * 16];
        u16x8 q1 = *(const u16x8*)&Qb[(size_t)d * HD + t * 16 + 8];
#pragma unroll
        for (int j = 0; j < 8; ++j) {
            qv[j] = bf2f(q0[j]) * scale;
            qv[8 + j] = bf2f(q1[j]) * scale;
        }
    }
    float ss = 0.f;
    float acc[16];
#pragma unroll
    for (int j = 0; j < 16; ++j) acc[j] = 0.f;

    const int nit = (end - beg + 7) >> 3;
    for (int it = 0; it < nit; ++it) {
        const int idx = beg + it * 8 + g;
        const bool act = idx < end;
        const int s = act ? csr[idx] : 0;
        const unsigned short* kvp = &KV[(size_t)s * 256 + t * 16];
        const u16x8 k0 = *(const u16x8*)kvp;
        const u16x8 k1 = *(const u16x8*)(kvp + 8);
        const u16x8 v0 = *(const u16x8*)(kvp + 128);
        const u16x8 v1 = *(const u16x8*)(kvp + 136);
        float p = 0.f;
#pragma unroll
        for (int j = 0; j < 8; ++j) {
            p = fmaf(bf2f(k0[j]), qv[j], p);
            p = fmaf(bf2f(k1[j]), qv[8 + j], p);
        }
#pragma unroll
        for (int mask = 1; mask < 8; mask <<= 1) p += __shfl_xor(p, mask, 64);
        const float e = act ? __expf(p) : 0.f;  // LN-scale scores: no max-sub needed in fp32
        ss += e;
#pragma unroll
        for (int j = 0; j < 8; ++j) {
            acc[j] = fmaf(e, bf2f(v0[j]), acc[j]);
            acc[8 + j] = fmaf(e, bf2f(v1[j]), acc[8 + j]);
        }
    }

#pragma unroll
    for (int mask = 8; mask <= 32; mask <<= 1) {
        ss += __shfl_xor(ss, mask, 64);
#pragma unroll
        for (int j = 0; j < 16; ++j) acc[j] += __shfl_xor(acc[j], mask, 64);
    }

    const float inv = (end > beg) ? 1.f / ss : 0.f;
    if (g == 0) {
        u16x8 o0, o1;
#pragma unroll
        for (int j = 0; j < 8; ++j) {
            o0[j] = f2bf(acc[j] * inv);
            o1[j] = f2bf(acc[8 + j] * inv);
        }
        *(u16x8*)&Mb[(size_t)d * HD + t * 16] = o0;
        *(u16x8*)&Mb[(size_t)d * HD + t * 16 + 8] = o1;
    }
}

// ---------------- launch ----------------
extern "C" void kernel_launch(void* const* d_in, const int* in_sizes, int n_in,
                              void* d_out, int out_size, void* d_ws, size_t ws_size,
                              hipStream_t stream) {
    const float* x    = (const float*)d_in[0];
    const void*  eix  = d_in[1];
    const float* Wn   = (const float*)d_in[2];
    const float* bn   = (const float*)d_in[3];
    const float* WQ   = (const float*)d_in[4];
    const float* bQ   = (const float*)d_in[5];
    const float* WK   = (const float*)d_in[6];
    const float* bK   = (const float*)d_in[7];
    const float* WV   = (const float*)d_in[8];
    const float* bV   = (const float*)d_in[9];
    const float* WO   = (const float*)d_in[10];
    const float* bO   = (const float*)d_in[11];
    const float* lng  = (const float*)d_in[12];
    const float* lnb  = (const float*)d_in[13];
    const float* Wout = (const float*)d_in[14];
    const float* bout = (const float*)d_in[15];

    const int n = in_sizes[0] / HD;
    const int E = in_sizes[1] / 2;
    const int L = 4;
    const int NBINS = (n + 511) >> 9;

    char* p = (char*)d_ws;
    auto alloc = [&](size_t bytes) -> void* {
        void* r = (void*)p;
        p += (bytes + 255) & ~(size_t)255;
        return r;
    };
    unsigned short* hb = (unsigned short*)alloc((size_t)n * HD * 2);
    unsigned short* qb = (unsigned short*)alloc((size_t)n * HD * 2);
    unsigned short* kv = (unsigned short*)alloc((size_t)n * HD * 4);  // interleaved K|V
    unsigned short* mb = (unsigned short*)alloc((size_t)n * HD * 2);
    int* ssrc   = (int*)alloc((size_t)E * 4);
    int* sdst   = (int*)alloc((size_t)E * 4);
    int* csr    = (int*)alloc((size_t)E * 4);
    int* rowptr = (int*)alloc((size_t)(n + 1) * 4);
    int* btot   = (int*)alloc(256 * 4);
    int* bbase  = (int*)alloc(257 * 4);
    int* bcur   = (int*)alloc(256 * 4);
    int* flag   = (int*)alloc(256);
    unsigned short* wt = (unsigned short*)alloc(18 * 16384 * 2);

    const int EB = (E + EPB - 1) / EPB;
    const int nw = (n + 3) / 4;
    const int nl = (n + 63) / 64;

    detect_kernel<<<1, 256, 0, stream>>>((const unsigned*)eix, flag);
    hipMemsetAsync(btot, 0, 256 * 4, stream);
    p1_count<<<EB, 256, 0, stream>>>(eix, flag, E, btot, NBINS);
    p1_scan<<<1, 256, 0, stream>>>(btot, bbase, bcur, rowptr, NBINS, n, E);
    p1_scatter<<<EB, 256, 0, stream>>>(eix, flag, E, bcur, ssrc, sdst);
    p2_build<<<NBINS, 256, 0, stream>>>(sdst, ssrc, bbase, rowptr, csr, n);

    WPtrs wp;
    wp.p[0] = Wn; wp.p[1] = WQ; wp.p[2] = WK; wp.p[3] = WV; wp.p[4] = WO; wp.p[5] = Wout;
    wtrans_all<<<(18 * 16384 + 255) / 256, 256, 0, stream>>>(wp, wt);

    // hb = bf16(x @ Wn + bn)
    lin_lds<true, false, false, true><<<nl, 256, 0, stream>>>(
        x, wt, bn, nullptr, nullptr, nullptr, nullptr, hb, n);

    for (int l = 0; l < L; ++l) {
        lin3_lds<<<nl, 256, 0, stream>>>(
            hb, wt + (size_t)(1 + 3 * l) * 16384, bQ + l * HD, bK + l * HD, bV + l * HD,
            qb, kv, n);
        attn_kernel<<<nw, 256, 0, stream>>>(qb, kv, rowptr, csr, mb, n);
        lin_lds<false, true, false, true><<<nl, 256, 0, stream>>>(
            mb, wt + (size_t)(13 + l) * 16384, bO + l * HD, lng + l * HD, lnb + l * HD,
            hb, nullptr, hb, n);
    }
    lin_lds<false, false, true, false><<<nl, 256, 0, stream>>>(
        hb, wt + (size_t)17 * 16384, bout, nullptr, nullptr, nullptr, (float*)d_out, nullptr, n);
}